// Round 1
// baseline (20.905 us; speedup 1.0000x reference)
//
#include <hip/hip_runtime.h>

#define NUM_ROIS 8192
#define NUM_CLASSES 20
#define FG_THRESH 0.5f
#define BG_HI 0.5f
#define BG_LO 0.1f

// Kernel 1: per-class argmax over S[:, c] (first-occurrence-of-max semantics,
// matching jnp.argmax). One block per class, 256 threads.
__global__ void roilabel_seed_argmax(const float* __restrict__ S,
                                     int* __restrict__ seeds) {
    const int c = blockIdx.x;   // class 0..19
    const int t = threadIdx.x;  // 0..255

    float best_v = -__builtin_inff();
    int best_i = NUM_ROIS;  // sentinel (never survives: every thread sees >=1 row)

    // Thread t scans rows t, t+256, ... (ascending) -> strict '>' keeps the
    // first (lowest-index) occurrence of the max within this thread.
    for (int r = t; r < NUM_ROIS; r += 256) {
        float v = S[r * NUM_CLASSES + c];
        if (v > best_v) { best_v = v; best_i = r; }
    }

    __shared__ float sv[256];
    __shared__ int   si[256];
    sv[t] = best_v;
    si[t] = best_i;
    __syncthreads();

    // Tree reduce; ties broken toward the smaller row index -> global
    // first-occurrence argmax.
    for (int off = 128; off > 0; off >>= 1) {
        if (t < off) {
            float v2 = sv[t + off];
            int   i2 = si[t + off];
            if (v2 > sv[t] || (v2 == sv[t] && i2 < si[t])) {
                sv[t] = v2;
                si[t] = i2;
            }
        }
        __syncthreads();
    }
    if (t == 0) seeds[c] = si[0];
}

// Kernel 2: per-ROI best seed class -> label/weight.
// out[0:8192]       = RL as float32 (exact small integers)
// out[8192:16384]   = RW float32
__global__ void roilabel_assign(const float* __restrict__ U,
                                const float* __restrict__ L,
                                const float* __restrict__ CW,
                                const int* __restrict__ seeds,
                                float* __restrict__ out) {
    __shared__ int   s_seed[NUM_CLASSES];
    __shared__ int   s_valid[NUM_CLASSES];
    __shared__ float s_cw[NUM_CLASSES];

    const int t = threadIdx.x;
    if (t < NUM_CLASSES) {
        s_seed[t]  = seeds[t];
        s_valid[t] = (L[t] > 0.0f) ? 1 : 0;
        s_cw[t]    = CW[t];
    }
    __syncthreads();

    const int i = blockIdx.x * blockDim.x + t;
    if (i >= NUM_ROIS) return;

    const float* __restrict__ row = U + (size_t)i * NUM_ROIS;

    float best_iou = -2.0f;  // below the -1.0 "invalid" value
    int best_c = 0;
    #pragma unroll
    for (int c = 0; c < NUM_CLASSES; ++c) {
        float v = s_valid[c] ? row[s_seed[c]] : -1.0f;
        // strict '>' keeps the FIRST class among equal maxima (jnp.argmax axis=1)
        if (v > best_iou) { best_iou = v; best_c = c; }
    }

    const bool is_fg = (best_iou >= FG_THRESH);
    const bool is_bg = (best_iou < BG_HI) && (best_iou >= BG_LO);

    int   rl = is_fg ? (best_c + 1) : (is_bg ? 0 : -1);
    float rw = (is_fg || is_bg) ? s_cw[best_c] : 0.0f;

    out[i]            = (float)rl;
    out[NUM_ROIS + i] = rw;
}

extern "C" void kernel_launch(void* const* d_in, const int* in_sizes, int n_in,
                              void* d_out, int out_size, void* d_ws, size_t ws_size,
                              hipStream_t stream) {
    const float* S  = (const float*)d_in[0];  // [8192, 20]
    const float* U  = (const float*)d_in[1];  // [8192, 8192]
    const float* L  = (const float*)d_in[2];  // [1, 20]
    const float* CW = (const float*)d_in[3];  // [1, 20]
    float* out = (float*)d_out;               // [16384] = RL(8192) ++ RW(8192)
    int* seeds = (int*)d_ws;                  // 20 ints of scratch

    roilabel_seed_argmax<<<NUM_CLASSES, 256, 0, stream>>>(S, seeds);
    roilabel_assign<<<NUM_ROIS / 256, 256, 0, stream>>>(U, L, CW, seeds, out);
}